// Round 7
// baseline (215.968 us; speedup 1.0000x reference)
//
#include <hip/hip_runtime.h>
#include <hip/hip_bf16.h>

// ---------------------------------------------------------------------------
// conv_bf16   : feature (+W) fp32 -> bf16 (RNE), one flat pass
// CSR build (two-level; NPART=832 for occupancy):
//   p_hist / p_scan / p_scatter / local_csr
// gather_mm v2: block = 16 waves = 16 nodes. Each wave gathers ONE node
//   (full parallelism, bf16 reads) into LDS; waves 0..7 then MFMA one
//   16-col n-tile of the 16x128 output. No h round-trip.
// ---------------------------------------------------------------------------

#define BKT_SHIFT 7                 // 128 nodes per bucket
#define MAX_BKT   512               // >= ceil(50000/128)+1

typedef __attribute__((ext_vector_type(8))) short short8;
typedef __attribute__((ext_vector_type(4))) float float4v;

__device__ __forceinline__ unsigned short f2bf_rne(float f) {
    unsigned int u = __float_as_uint(f);
    u += 0x7FFFu + ((u >> 16) & 1u);
    return (unsigned short)(u >> 16);
}

// --- conv: flat fp32 -> bf16 for [feature (nf elems)] ++ [W (nw elems)] ---
__global__ __launch_bounds__(256) void conv_bf16_kernel(
    const float* __restrict__ feat, const float* __restrict__ W,
    unsigned short* __restrict__ out_bf, long nf, long nw)
{
    long i4 = ((long)blockIdx.x * 256 + threadIdx.x) * 4;
    if (i4 >= nf + nw) return;          // nf, nw both multiples of 4
    const float* srcp = (i4 < nf) ? (feat + i4) : (W + (i4 - nf));
    float4 v = *(const float4*)srcp;
    ushort4 o;
    o.x = f2bf_rne(v.x); o.y = f2bf_rne(v.y);
    o.z = f2bf_rne(v.z); o.w = f2bf_rne(v.w);
    *(ushort4*)(out_bf + i4) = o;
}

// --- p_hist: per-block LDS histogram of dst buckets -> global bucket_cnt ---
__global__ __launch_bounds__(256) void p_hist_kernel(
    const int* __restrict__ dst, int* __restrict__ bucket_cnt,
    int n_edges, int nb, int chunk)
{
    __shared__ int lcnt[MAX_BKT];
    int tid = threadIdx.x;
    int e0  = blockIdx.x * chunk;
    int e1  = min(e0 + chunk, n_edges);

    for (int i = tid; i < nb; i += 256) lcnt[i] = 0;
    __syncthreads();
    for (int e = e0 + tid; e < e1; e += 256)
        atomicAdd(&lcnt[dst[e] >> BKT_SHIFT], 1);
    __syncthreads();
    for (int i = tid; i < nb; i += 256) {
        int c = lcnt[i];
        if (c) atomicAdd(&bucket_cnt[i], c);
    }
}

// --- p_scan: one wave, 8 buckets/lane; writes bucket_off[0..nb] + cursor ---
__global__ __launch_bounds__(64) void p_scan_kernel(
    const int* __restrict__ bucket_cnt, int* __restrict__ bucket_off,
    int* __restrict__ bucket_cursor, int nb)
{
    int lane = threadIdx.x;
    const int PER = 8;
    int base = lane * PER;
    int v[PER];
    int sum = 0;
    #pragma unroll
    for (int j = 0; j < PER; j++) {
        v[j] = (base + j < nb) ? bucket_cnt[base + j] : 0;
        sum += v[j];
    }
    int x = sum;
    #pragma unroll
    for (int off = 1; off < 64; off <<= 1) {
        int y = __shfl_up(x, off, 64);
        if (lane >= off) x += y;
    }
    int run = x - sum;
    #pragma unroll
    for (int j = 0; j < PER; j++) {
        int idx = base + j;
        if (idx <= nb) {
            bucket_off[idx] = run;
            if (idx < nb) bucket_cursor[idx] = run;
        }
        run += v[j];
    }
}

// --- p_scatter: partition edges into bucket regions as (dst,src) pairs ---
__global__ __launch_bounds__(256) void p_scatter_kernel(
    const int* __restrict__ src, const int* __restrict__ dst,
    int* __restrict__ bucket_cursor, int2* __restrict__ pairs,
    int n_edges, int nb, int chunk)
{
    __shared__ int lcnt[MAX_BKT];
    __shared__ int lcur[MAX_BKT];
    int tid = threadIdx.x;
    int e0  = blockIdx.x * chunk;
    int e1  = min(e0 + chunk, n_edges);

    for (int i = tid; i < nb; i += 256) lcnt[i] = 0;
    __syncthreads();
    for (int e = e0 + tid; e < e1; e += 256)
        atomicAdd(&lcnt[dst[e] >> BKT_SHIFT], 1);
    __syncthreads();
    for (int i = tid; i < nb; i += 256) {
        int c = lcnt[i];
        lcur[i] = c ? atomicAdd(&bucket_cursor[i], c) : 0;
    }
    __syncthreads();
    for (int e = e0 + tid; e < e1; e += 256) {
        int d = dst[e];
        int s = src[e];
        int pos = atomicAdd(&lcur[d >> BKT_SHIFT], 1);
        pairs[pos] = make_int2(d, s);
    }
}

// --- local_csr: per bucket (128 nodes) exact CSR via LDS hist + scan ---
__global__ __launch_bounds__(256) void local_csr_kernel(
    const int2* __restrict__ pairs, const int* __restrict__ bucket_off,
    int* __restrict__ offs, int* __restrict__ src_sorted,
    int n_nodes, int n_edges)
{
    __shared__ int hist[128];
    __shared__ int excl[128];
    __shared__ int curs[128];
    int b   = blockIdx.x;
    int tid = threadIdx.x;
    int node_base = b << BKT_SHIFT;
    int bstart = bucket_off[b];
    int bend   = bucket_off[b + 1];

    if (tid < 128) hist[tid] = 0;
    __syncthreads();
    for (int i = bstart + tid; i < bend; i += 256)
        atomicAdd(&hist[pairs[i].x - node_base], 1);
    __syncthreads();
    if (tid < 64) {
        int v0 = hist[2 * tid];
        int v1 = hist[2 * tid + 1];
        int s  = v0 + v1;
        int x  = s;
        #pragma unroll
        for (int off = 1; off < 64; off <<= 1) {
            int y = __shfl_up(x, off, 64);
            if (tid >= off) x += y;
        }
        int e0 = x - s;
        excl[2 * tid]     = e0;
        excl[2 * tid + 1] = e0 + v0;
    }
    __syncthreads();
    if (tid < 128) {
        int pos = bstart + excl[tid];
        int node = node_base + tid;
        if (node < n_nodes) offs[node] = pos;
        curs[tid] = pos;
    }
    __syncthreads();
    for (int i = bstart + tid; i < bend; i += 256) {
        int2 p = pairs[i];
        int pos = atomicAdd(&curs[p.x - node_base], 1);
        src_sorted[pos] = p.y;
    }
    if (b == 0 && tid == 0) offs[n_nodes] = n_edges;
}

// --- FUSED gather + MFMA projection, v2 (full gather parallelism) ---
// Block = 16 waves = 16 nodes. Wave w gathers node node0+w (lane owns cols
// 2*lane, 2*lane+1; fp32 accumulate) into LDS row w (bf16, stride 136).
// After barrier, waves 0..7 each compute D[16x16] for n-tile t=w via 4
// chained 16x16x32 bf16 MFMAs (A from LDS, B=W rows from global/L1).
// D layout: col=lane&15, row=quad*4+reg (verified m89/m91).
#define HT_STRIDE 136

__global__ __launch_bounds__(1024, 4) void gcn_gather_mm_kernel(
    const float* __restrict__ feat_f32,
    const unsigned short* __restrict__ feat_bf, int use_bf16,
    const int* __restrict__ offs, const int* __restrict__ src_sorted,
    const unsigned short* __restrict__ w_bf, const float* __restrict__ bias,
    float* __restrict__ out, int n_nodes)
{
    __shared__ unsigned short htile[16 * HT_STRIDE];   // 4352 B

    int tid   = threadIdx.x;
    int lane  = tid & 63;
    int w     = tid >> 6;          // wave id 0..15 == local row
    int node0 = blockIdx.x * 16;
    int node  = node0 + w;

    // ---- Phase 1: each wave gathers ONE node ----
    float accx = 0.f, accy = 0.f;
    if (node < n_nodes) {
        int beg = offs[node];
        int end = offs[node + 1];
        int i = beg;
        if (use_bf16) {
            for (; i + 3 < end; i += 4) {
                int s0 = src_sorted[i],     s1 = src_sorted[i + 1];
                int s2 = src_sorted[i + 2], s3 = src_sorted[i + 3];
                unsigned int u0 = *(const unsigned int*)(feat_bf + (size_t)s0 * 128 + lane * 2);
                unsigned int u1 = *(const unsigned int*)(feat_bf + (size_t)s1 * 128 + lane * 2);
                unsigned int u2 = *(const unsigned int*)(feat_bf + (size_t)s2 * 128 + lane * 2);
                unsigned int u3 = *(const unsigned int*)(feat_bf + (size_t)s3 * 128 + lane * 2);
                accx += __uint_as_float(u0 << 16) + __uint_as_float(u1 << 16)
                      + __uint_as_float(u2 << 16) + __uint_as_float(u3 << 16);
                accy += __uint_as_float(u0 & 0xFFFF0000u) + __uint_as_float(u1 & 0xFFFF0000u)
                      + __uint_as_float(u2 & 0xFFFF0000u) + __uint_as_float(u3 & 0xFFFF0000u);
            }
            for (; i < end; ++i) {
                unsigned int u = *(const unsigned int*)(feat_bf + (size_t)src_sorted[i] * 128 + lane * 2);
                accx += __uint_as_float(u << 16);
                accy += __uint_as_float(u & 0xFFFF0000u);
            }
        } else {
            for (; i + 3 < end; i += 4) {
                int s0 = src_sorted[i],     s1 = src_sorted[i + 1];
                int s2 = src_sorted[i + 2], s3 = src_sorted[i + 3];
                float2 v0 = ((const float2*)(feat_f32 + (size_t)s0 * 128))[lane];
                float2 v1 = ((const float2*)(feat_f32 + (size_t)s1 * 128))[lane];
                float2 v2 = ((const float2*)(feat_f32 + (size_t)s2 * 128))[lane];
                float2 v3 = ((const float2*)(feat_f32 + (size_t)s3 * 128))[lane];
                accx += (v0.x + v1.x) + (v2.x + v3.x);
                accy += (v0.y + v1.y) + (v2.y + v3.y);
            }
            for (; i < end; ++i) {
                float2 v = ((const float2*)(feat_f32 + (size_t)src_sorted[i] * 128))[lane];
                accx += v.x;
                accy += v.y;
            }
        }
    }
    unsigned int px = (unsigned int)f2bf_rne(accx);
    unsigned int py = (unsigned int)f2bf_rne(accy) << 16;
    *(unsigned int*)(htile + w * HT_STRIDE + lane * 2) = px | py;

    __syncthreads();

    // ---- Phase 2: waves 0..7 each do n-tile t = w (cols 16w..16w+15) ----
    if (w < 8) {
        int lane15 = lane & 15;
        int quad   = lane >> 4;

        float4v acc = {0.f, 0.f, 0.f, 0.f};
        #pragma unroll
        for (int kk = 0; kk < 4; kk++) {
            short8 afrag = *(const short8*)(htile + lane15 * HT_STRIDE + kk * 32 + quad * 8);
            short8 bfrag = *(const short8*)(w_bf + (size_t)(w * 16 + lane15) * 128 + kk * 32 + quad * 8);
            acc = __builtin_amdgcn_mfma_f32_16x16x32_bf16(afrag, bfrag, acc, 0, 0, 0);
        }
        float bv = bias[w * 16 + lane15];
        #pragma unroll
        for (int r = 0; r < 4; r++) {
            int row = node0 + quad * 4 + r;
            if (row < n_nodes)
                out[(size_t)row * 128 + w * 16 + lane15] = acc[r] + bv;
        }
    }
}

extern "C" void kernel_launch(void* const* d_in, const int* in_sizes, int n_in,
                              void* d_out, int out_size, void* d_ws, size_t ws_size,
                              hipStream_t stream) {
    const float* feature = (const float*)d_in[0];
    const int*   src     = (const int*)d_in[1];
    const int*   dst     = (const int*)d_in[2];
    const float* W       = (const float*)d_in[3];
    const float* b       = (const float*)d_in[4];

    const int D  = 128;
    int n_nodes  = in_sizes[0] / D;
    int n_edges  = in_sizes[1];
    int nb       = (n_nodes + 127) >> BKT_SHIFT;

    float* out = (float*)d_out;

    long nf = (long)n_nodes * D;      // feature elems (mult of 4)
    long nw = (long)D * D;            // W elems (16384)

    // ws layout: [feature_bf nf?] [w_bf nw] [pairs E int2] [src_sorted E]
    //            [offs N+1] [bucket_cnt 512] [bucket_off 513] [bucket_cur 512]
    size_t tail_bytes = (size_t)n_edges * 8 + (size_t)n_edges * 4 +
                        (size_t)(n_nodes + 1) * 4 + (size_t)(3 * MAX_BKT + 1) * 4;
    size_t need_full  = (size_t)(nf + nw) * 2 + tail_bytes;
    int use_bf16 = (ws_size >= need_full) ? 1 : 0;   // constant across calls

    unsigned short* bf_base    = (unsigned short*)d_ws;
    long            nf_eff     = use_bf16 ? nf : 0;
    unsigned short* feature_bf = bf_base;            // valid only if use_bf16
    unsigned short* w_bf       = bf_base + nf_eff;
    int2* pairs        = (int2*)(bf_base + nf_eff + nw);
    int* src_sorted    = (int*)(pairs + n_edges);
    int* offs          = src_sorted + n_edges;
    int* bucket_cnt    = offs + (n_nodes + 1);
    int* bucket_off    = bucket_cnt + MAX_BKT;
    int* bucket_cursor = bucket_off + (MAX_BKT + 1);

    hipMemsetAsync(bucket_cnt, 0, (size_t)nb * sizeof(int), stream);

    // bf16 conversion of feature (optional) + W
    {
        long total = nf_eff + nw;
        int blocks = (int)((total / 4 + 255) / 256);
        conv_bf16_kernel<<<blocks, 256, 0, stream>>>(feature, W, bf_base, nf_eff, nw);
    }

    // NPART=832: ~962 edges/block, ~13 waves/CU (was 128 blocks = 2 waves/CU,
    // the hidden ~110 us in rounds 5/6).
    const int NPART = 832;
    int chunk = (n_edges + NPART - 1) / NPART;

    p_hist_kernel<<<NPART, 256, 0, stream>>>(dst, bucket_cnt, n_edges, nb, chunk);
    p_scan_kernel<<<1, 64, 0, stream>>>(bucket_cnt, bucket_off, bucket_cursor, nb);
    p_scatter_kernel<<<NPART, 256, 0, stream>>>(src, dst, bucket_cursor, pairs,
                                                n_edges, nb, chunk);
    local_csr_kernel<<<nb, 256, 0, stream>>>(pairs, bucket_off, offs, src_sorted,
                                             n_nodes, n_edges);

    {
        int blocks = (n_nodes + 15) / 16;   // 3125 blocks, 16 waves each
        gcn_gather_mm_kernel<<<blocks, 1024, 0, stream>>>(
            feature, feature_bf, use_bf16, offs, src_sorted, w_bf, b, out, n_nodes);
    }
}

// Round 8
// 187.677 us; speedup vs baseline: 1.1507x; 1.1507x over previous
//
#include <hip/hip_runtime.h>
#include <hip/hip_bf16.h>

// ---------------------------------------------------------------------------
// 5-dispatch pipeline (was 8 — ~12us graph-node overhead each):
//  1) conv_hist : blocks [0,128) = per-partition LDS hist of dst buckets ->
//                 cnt128[bucket][part] (NO atomics, no memset needed);
//                 blocks [128,..) = fp32->bf16 conv of feature+W.
//  2) scan128   : one block: bucket totals, bucket_off, and exact
//                 per-(bucket,partition) start cursors (cursor128).
//  3) p_scatter : NPART=128 (16-edge=128B runs, round-5 write locality),
//                 cursor-seeded, zero global atomics.
//  4) local_csr : per-bucket exact CSR via LDS hist+scan (proven).
//  5) gather_mm : 16 waves = 16 nodes, one wave per node gather (bf16),
//                 MFMA 16x16x32_bf16 projection, fp32 store (proven, 58us).
// ---------------------------------------------------------------------------

#define BKT_SHIFT 7                 // 128 nodes per bucket
#define MAX_BKT   512               // >= ceil(50000/128)+1
#define NPART     128               // partition blocks (write-locality sweet spot)

typedef __attribute__((ext_vector_type(8))) short short8;
typedef __attribute__((ext_vector_type(4))) float float4v;

__device__ __forceinline__ unsigned short f2bf_rne(float f) {
    unsigned int u = __float_as_uint(f);
    u += 0x7FFFu + ((u >> 16) & 1u);
    return (unsigned short)(u >> 16);
}

// --- 1) fused conv + per-partition hist ---
__global__ __launch_bounds__(256) void conv_hist_kernel(
    const float* __restrict__ feat, const float* __restrict__ W,
    unsigned short* __restrict__ out_bf, long nf, long nw,
    const int* __restrict__ dst, int* __restrict__ cnt128,
    int n_edges, int nb, int chunk)
{
    if ((int)blockIdx.x < NPART) {
        // hist partition p
        __shared__ int lcnt[MAX_BKT];
        int tid = threadIdx.x;
        int p   = blockIdx.x;
        int e0  = p * chunk;
        int e1  = min(e0 + chunk, n_edges);
        for (int i = tid; i < nb; i += 256) lcnt[i] = 0;
        __syncthreads();
        for (int e = e0 + tid; e < e1; e += 256)
            atomicAdd(&lcnt[dst[e] >> BKT_SHIFT], 1);
        __syncthreads();
        for (int i = tid; i < nb; i += 256)
            cnt128[i * NPART + p] = lcnt[i];     // bucket-major, no atomics
    } else {
        long i4 = ((long)(blockIdx.x - NPART) * 256 + threadIdx.x) * 4;
        if (i4 >= nf + nw) return;               // nf, nw multiples of 4
        const float* srcp = (i4 < nf) ? (feat + i4) : (W + (i4 - nf));
        float4 v = *(const float4*)srcp;
        ushort4 o;
        o.x = f2bf_rne(v.x); o.y = f2bf_rne(v.y);
        o.z = f2bf_rne(v.z); o.w = f2bf_rne(v.w);
        *(ushort4*)(out_bf + i4) = o;
    }
}

// --- 2) scan128: totals -> bucket_off; per-(bucket,part) cursors ---
__global__ __launch_bounds__(1024) void scan128_kernel(
    const int* __restrict__ cnt128, int* __restrict__ cursor128,
    int* __restrict__ bucket_off, int nb)
{
    __shared__ int tot[MAX_BKT];
    __shared__ int toff[MAX_BKT + 1];
    int tid  = threadIdx.x;
    int lane = tid & 63;
    int wid  = tid >> 6;

    // Phase 1: bucket totals (wave j-strided; 2 partitions per lane)
    for (int j = wid; j < nb; j += 16) {
        int2 v = *(const int2*)(cnt128 + j * NPART + 2 * lane);
        int s = v.x + v.y;
        #pragma unroll
        for (int off = 1; off < 64; off <<= 1) s += __shfl_xor(s, off, 64);
        if (lane == 0) tot[j] = s;
    }
    __syncthreads();
    // Phase 2: exclusive scan of totals (wave 0, 8 per lane)
    if (wid == 0) {
        const int PER = 8;
        int base = lane * PER;
        int v[PER];
        int sum = 0;
        #pragma unroll
        for (int k = 0; k < PER; k++) {
            v[k] = (base + k < nb) ? tot[base + k] : 0;
            sum += v[k];
        }
        int x = sum;
        #pragma unroll
        for (int off = 1; off < 64; off <<= 1) {
            int y = __shfl_up(x, off, 64);
            if (lane >= off) x += y;
        }
        int run = x - sum;
        #pragma unroll
        for (int k = 0; k < PER; k++) {
            int idx = base + k;
            if (idx <= nb) { toff[idx] = run; bucket_off[idx] = run; }
            run += v[k];
        }
    }
    __syncthreads();
    // Phase 3: per-bucket exclusive scan over partitions + bucket base
    for (int j = wid; j < nb; j += 16) {
        int2 v = *(const int2*)(cnt128 + j * NPART + 2 * lane);
        int s = v.x + v.y;
        int x = s;
        #pragma unroll
        for (int off = 1; off < 64; off <<= 1) {
            int y = __shfl_up(x, off, 64);
            if (lane >= off) x += y;
        }
        int e0 = x - s + toff[j];
        int2 o;
        o.x = e0;
        o.y = e0 + v.x;
        *(int2*)(cursor128 + j * NPART + 2 * lane) = o;
    }
}

// --- 3) p_scatter: partition edges into bucket regions (no global atomics) ---
__global__ __launch_bounds__(256) void p_scatter_kernel(
    const int* __restrict__ src, const int* __restrict__ dst,
    const int* __restrict__ cursor128, int2* __restrict__ pairs,
    int n_edges, int nb, int chunk)
{
    __shared__ int lcur[MAX_BKT];
    int tid = threadIdx.x;
    int p   = blockIdx.x;
    int e0  = p * chunk;
    int e1  = min(e0 + chunk, n_edges);

    for (int i = tid; i < nb; i += 256) lcur[i] = cursor128[i * NPART + p];
    __syncthreads();
    for (int e = e0 + tid; e < e1; e += 256) {
        int d = dst[e];
        int s = src[e];
        int pos = atomicAdd(&lcur[d >> BKT_SHIFT], 1);   // LDS atomic only
        pairs[pos] = make_int2(d, s);
    }
}

// --- 4) local_csr: per bucket (128 nodes) exact CSR via LDS hist + scan ---
__global__ __launch_bounds__(256) void local_csr_kernel(
    const int2* __restrict__ pairs, const int* __restrict__ bucket_off,
    int* __restrict__ offs, int* __restrict__ src_sorted,
    int n_nodes, int n_edges)
{
    __shared__ int hist[128];
    __shared__ int excl[128];
    __shared__ int curs[128];
    int b   = blockIdx.x;
    int tid = threadIdx.x;
    int node_base = b << BKT_SHIFT;
    int bstart = bucket_off[b];
    int bend   = bucket_off[b + 1];

    if (tid < 128) hist[tid] = 0;
    __syncthreads();
    for (int i = bstart + tid; i < bend; i += 256)
        atomicAdd(&hist[pairs[i].x - node_base], 1);
    __syncthreads();
    if (tid < 64) {
        int v0 = hist[2 * tid];
        int v1 = hist[2 * tid + 1];
        int s  = v0 + v1;
        int x  = s;
        #pragma unroll
        for (int off = 1; off < 64; off <<= 1) {
            int y = __shfl_up(x, off, 64);
            if (tid >= off) x += y;
        }
        int e0 = x - s;
        excl[2 * tid]     = e0;
        excl[2 * tid + 1] = e0 + v0;
    }
    __syncthreads();
    if (tid < 128) {
        int pos = bstart + excl[tid];
        int node = node_base + tid;
        if (node < n_nodes) offs[node] = pos;
        curs[tid] = pos;
    }
    __syncthreads();
    for (int i = bstart + tid; i < bend; i += 256) {
        int2 p = pairs[i];
        int pos = atomicAdd(&curs[p.x - node_base], 1);
        src_sorted[pos] = p.y;
    }
    if (b == 0 && tid == 0) offs[n_nodes] = n_edges;
}

// --- 5) FUSED gather + MFMA projection (round-7 proven) ---
#define HT_STRIDE 136

__global__ __launch_bounds__(1024, 4) void gcn_gather_mm_kernel(
    const float* __restrict__ feat_f32,
    const unsigned short* __restrict__ feat_bf, int use_bf16,
    const int* __restrict__ offs, const int* __restrict__ src_sorted,
    const unsigned short* __restrict__ w_bf, const float* __restrict__ bias,
    float* __restrict__ out, int n_nodes)
{
    __shared__ unsigned short htile[16 * HT_STRIDE];   // 4352 B

    int tid   = threadIdx.x;
    int lane  = tid & 63;
    int w     = tid >> 6;          // wave id 0..15 == local row
    int node0 = blockIdx.x * 16;
    int node  = node0 + w;

    float accx = 0.f, accy = 0.f;
    if (node < n_nodes) {
        int beg = offs[node];
        int end = offs[node + 1];
        int i = beg;
        if (use_bf16) {
            for (; i + 3 < end; i += 4) {
                int s0 = src_sorted[i],     s1 = src_sorted[i + 1];
                int s2 = src_sorted[i + 2], s3 = src_sorted[i + 3];
                unsigned int u0 = *(const unsigned int*)(feat_bf + (size_t)s0 * 128 + lane * 2);
                unsigned int u1 = *(const unsigned int*)(feat_bf + (size_t)s1 * 128 + lane * 2);
                unsigned int u2 = *(const unsigned int*)(feat_bf + (size_t)s2 * 128 + lane * 2);
                unsigned int u3 = *(const unsigned int*)(feat_bf + (size_t)s3 * 128 + lane * 2);
                accx += __uint_as_float(u0 << 16) + __uint_as_float(u1 << 16)
                      + __uint_as_float(u2 << 16) + __uint_as_float(u3 << 16);
                accy += __uint_as_float(u0 & 0xFFFF0000u) + __uint_as_float(u1 & 0xFFFF0000u)
                      + __uint_as_float(u2 & 0xFFFF0000u) + __uint_as_float(u3 & 0xFFFF0000u);
            }
            for (; i < end; ++i) {
                unsigned int u = *(const unsigned int*)(feat_bf + (size_t)src_sorted[i] * 128 + lane * 2);
                accx += __uint_as_float(u << 16);
                accy += __uint_as_float(u & 0xFFFF0000u);
            }
        } else {
            for (; i + 3 < end; i += 4) {
                int s0 = src_sorted[i],     s1 = src_sorted[i + 1];
                int s2 = src_sorted[i + 2], s3 = src_sorted[i + 3];
                float2 v0 = ((const float2*)(feat_f32 + (size_t)s0 * 128))[lane];
                float2 v1 = ((const float2*)(feat_f32 + (size_t)s1 * 128))[lane];
                float2 v2 = ((const float2*)(feat_f32 + (size_t)s2 * 128))[lane];
                float2 v3 = ((const float2*)(feat_f32 + (size_t)s3 * 128))[lane];
                accx += (v0.x + v1.x) + (v2.x + v3.x);
                accy += (v0.y + v1.y) + (v2.y + v3.y);
            }
            for (; i < end; ++i) {
                float2 v = ((const float2*)(feat_f32 + (size_t)src_sorted[i] * 128))[lane];
                accx += v.x;
                accy += v.y;
            }
        }
    }
    unsigned int px = (unsigned int)f2bf_rne(accx);
    unsigned int py = (unsigned int)f2bf_rne(accy) << 16;
    *(unsigned int*)(htile + w * HT_STRIDE + lane * 2) = px | py;

    __syncthreads();

    if (w < 8) {
        int lane15 = lane & 15;
        int quad   = lane >> 4;

        float4v acc = {0.f, 0.f, 0.f, 0.f};
        #pragma unroll
        for (int kk = 0; kk < 4; kk++) {
            short8 afrag = *(const short8*)(htile + lane15 * HT_STRIDE + kk * 32 + quad * 8);
            short8 bfrag = *(const short8*)(w_bf + (size_t)(w * 16 + lane15) * 128 + kk * 32 + quad * 8);
            acc = __builtin_amdgcn_mfma_f32_16x16x32_bf16(afrag, bfrag, acc, 0, 0, 0);
        }
        float bv = bias[w * 16 + lane15];
        #pragma unroll
        for (int r = 0; r < 4; r++) {
            int row = node0 + quad * 4 + r;
            if (row < n_nodes)
                out[(size_t)row * 128 + w * 16 + lane15] = acc[r] + bv;
        }
    }
}

extern "C" void kernel_launch(void* const* d_in, const int* in_sizes, int n_in,
                              void* d_out, int out_size, void* d_ws, size_t ws_size,
                              hipStream_t stream) {
    const float* feature = (const float*)d_in[0];
    const int*   src     = (const int*)d_in[1];
    const int*   dst     = (const int*)d_in[2];
    const float* W       = (const float*)d_in[3];
    const float* b       = (const float*)d_in[4];

    const int D  = 128;
    int n_nodes  = in_sizes[0] / D;
    int n_edges  = in_sizes[1];
    int nb       = (n_nodes + 127) >> BKT_SHIFT;   // 391

    float* out = (float*)d_out;

    long nf = (long)n_nodes * D;      // feature elems (mult of 4)
    long nw = (long)D * D;            // W elems

    // ws: [feature_bf nf?] [w_bf nw] [pairs E int2] [src_sorted E] [offs N+1]
    //     [cnt128 512*128] [cursor128 512*128] [bucket_off 513]
    size_t tail_bytes = (size_t)n_edges * 8 + (size_t)n_edges * 4 +
                        (size_t)(n_nodes + 1) * 4 +
                        (size_t)(2 * MAX_BKT * NPART + MAX_BKT + 1) * 4;
    size_t need_full  = (size_t)(nf + nw) * 2 + tail_bytes;
    int use_bf16 = (ws_size >= need_full) ? 1 : 0;   // constant across calls

    unsigned short* bf_base    = (unsigned short*)d_ws;
    long            nf_eff     = use_bf16 ? nf : 0;
    unsigned short* feature_bf = bf_base;            // valid only if use_bf16
    unsigned short* w_bf       = bf_base + nf_eff;
    int2* pairs        = (int2*)(bf_base + nf_eff + nw);
    int* src_sorted    = (int*)(pairs + n_edges);
    int* offs          = src_sorted + n_edges;
    int* cnt128        = offs + (n_nodes + 1);
    int* cursor128     = cnt128 + MAX_BKT * NPART;
    int* bucket_off    = cursor128 + MAX_BKT * NPART;

    int chunk = (n_edges + NPART - 1) / NPART;   // 6250

    // 1) conv + hist (no memset: cnt128 fully overwritten for i<nb, p<NPART)
    {
        long conv_blocks = ((nf_eff + nw) / 4 + 255) / 256;
        int grid = NPART + (int)conv_blocks;
        conv_hist_kernel<<<grid, 256, 0, stream>>>(
            feature, W, bf_base, nf_eff, nw, dst, cnt128, n_edges, nb, chunk);
    }

    // 2) scan
    scan128_kernel<<<1, 1024, 0, stream>>>(cnt128, cursor128, bucket_off, nb);

    // 3) scatter (no global atomics)
    p_scatter_kernel<<<NPART, 256, 0, stream>>>(src, dst, cursor128, pairs,
                                                n_edges, nb, chunk);

    // 4) per-bucket CSR
    local_csr_kernel<<<nb, 256, 0, stream>>>(pairs, bucket_off, offs, src_sorted,
                                             n_nodes, n_edges);

    // 5) fused gather + projection
    {
        int blocks = (n_nodes + 15) / 16;   // 3125 blocks, 16 waves each
        gcn_gather_mm_kernel<<<blocks, 1024, 0, stream>>>(
            feature, feature_bf, use_bf16, offs, src_sorted, w_bf, b, out, n_nodes);
    }
}